// Round 6
// baseline (139.622 us; speedup 1.0000x reference)
//
#include <hip/hip_runtime.h>
#include <hip/hip_bf16.h>

#define NB 16
#define VOX 884736        // 96*96*96
#define NPTS 4096
#define CHUNK 1024
#define NCHUNK 864        // VOX / CHUNK

typedef _Float16 f16x8 __attribute__((ext_vector_type(8)));
typedef _Float16 f16x4 __attribute__((ext_vector_type(4)));
typedef float f32x4 __attribute__((ext_vector_type(4)));

// ---------------- count + bitmask ----------------

__global__ __launch_bounds__(256) void count_kernel(const float* __restrict__ vol,
                                                    int* __restrict__ counts,
                                                    unsigned long long* __restrict__ bits) {
    int blk = blockIdx.x;  // b*NCHUNK + c
    const float4* v4 = (const float4*)(vol + (size_t)blk * CHUNK);
    float4 v = v4[threadIdx.x];
    int nib = (v.x > 0.5f) | ((v.y > 0.5f) << 1) | ((v.z > 0.5f) << 2) | ((v.w > 0.5f) << 3);
    __shared__ unsigned char nibs[256];
    nibs[threadIdx.x] = (unsigned char)nib;
    int cnt = __popc(nib);
    for (int off = 32; off; off >>= 1) cnt += __shfl_down(cnt, off, 64);
    __shared__ int s[4];
    if ((threadIdx.x & 63) == 0) s[threadIdx.x >> 6] = cnt;
    __syncthreads();
    if (threadIdx.x < 16) {
        unsigned long long wd = 0;
        #pragma unroll
        for (int i = 0; i < 16; i++)
            wd |= (unsigned long long)nibs[threadIdx.x * 16 + i] << (4 * i);
        bits[(size_t)blk * 16 + threadIdx.x] = wd;
    }
    if (threadIdx.x == 0) counts[blk] = s[0] + s[1] + s[2] + s[3];
}

__global__ __launch_bounds__(1024) void scan_kernel(const int* __restrict__ counts,
                                                    int* __restrict__ prefix,
                                                    int* __restrict__ totals) {
    __shared__ int s[1024];
    int b = blockIdx.x, t = threadIdx.x;
    int v = (t < NCHUNK) ? counts[b * NCHUNK + t] : 0;
    s[t] = v;
    __syncthreads();
    for (int off = 1; off < 1024; off <<= 1) {
        int x = (t >= off) ? s[t - off] : 0;
        __syncthreads();
        s[t] += x;
        __syncthreads();
    }
    if (t < NCHUNK) prefix[b * NCHUNK + t] = s[t] - v;   // exclusive
    if (t == NCHUNK - 1) totals[b] = s[t];
}

// ---------------- points via bitmask rank-select, fused conv1 stats ----------------

__global__ __launch_bounds__(256) void points_kernel(const unsigned long long* __restrict__ bits,
                                                     const int* __restrict__ prefix,
                                                     const int* __restrict__ totals,
                                                     const float* __restrict__ w1,
                                                     float* __restrict__ pts,
                                                     float* __restrict__ pstat1) {
    int b = blockIdx.x >> 4;
    int pc = blockIdx.x & 15;
    int p = pc * 256 + threadIdx.x;
    __shared__ int spref[NCHUNK];
    __shared__ float sw1[192];
    for (int i = threadIdx.x; i < NCHUNK; i += 256) spref[i] = prefix[b * NCHUNK + i];
    if (threadIdx.x < 192) sw1[threadIdx.x] = w1[threadIdx.x];
    __syncthreads();
    int n = totals[b];
    float px = 0.f, py = 0.f, pz = 0.f;
    if (n > 0) {
        int k;
        if (n >= NPTS) {
            float t = (float)p * ((float)n - 1.0f);
            t = t / 4095.0f;
            k = (int)t;
            if (k > n - 1) k = n - 1;
            if (k < 0) k = 0;
        } else {
            k = p % n;
        }
        int lo = 0, hi = NCHUNK - 1;
        while (lo < hi) {
            int mid = (lo + hi + 1) >> 1;
            if (spref[mid] <= k) lo = mid; else hi = mid - 1;
        }
        int rr = k - spref[lo];
        const unsigned long long* wb = bits + ((size_t)b * NCHUNK + lo) * 16;
        unsigned long long chosen = 0;
        int wordidx = 0;
        bool found = false;
        #pragma unroll
        for (int w = 0; w < 16; w++) {
            unsigned long long m = wb[w];
            int pcnt = __popcll(m);
            bool take = (!found) && (rr < pcnt);
            if (take) { chosen = m; wordidx = w; found = true; }
            if (!found) rr -= pcnt;
        }
        int pos = 0;
        unsigned long long m64 = chosen;
        int c = __popcll(m64 & 0xFFFFFFFFull);
        if (rr >= c) { pos = 32; rr -= c; m64 >>= 32; }
        unsigned mm = (unsigned)m64;
        c = __popc(mm & 0xFFFFu); if (rr >= c) { pos += 16; rr -= c; mm >>= 16; }
        c = __popc(mm & 0xFFu);   if (rr >= c) { pos += 8;  rr -= c; mm >>= 8; }
        c = __popc(mm & 0xFu);    if (rr >= c) { pos += 4;  rr -= c; mm >>= 4; }
        c = __popc(mm & 0x3u);    if (rr >= c) { pos += 2;  rr -= c; mm >>= 2; }
        c = mm & 1u;              if (rr >= c) { pos += 1; }
        int flat = lo * CHUNK + wordidx * 64 + pos;
        int dd = flat / 9216;           // 96*96
        int rem = flat - dd * 9216;
        int hh = rem / 96;
        int ww = rem - hh * 96;
        px = (float)dd / 95.0f * 2.0f - 1.0f;
        py = (float)hh / 95.0f * 2.0f - 1.0f;
        pz = (float)ww / 95.0f * 2.0f - 1.0f;
    }
    pts[((size_t)b * 3 + 0) * NPTS + p] = px;
    pts[((size_t)b * 3 + 1) * NPTS + p] = py;
    pts[((size_t)b * 3 + 2) * NPTS + p] = pz;
    // fused conv1 GN partial stats
    float s[8] = {}, q[8] = {};
    #pragma unroll
    for (int o = 0; o < 64; o++) {
        float a = sw1[o * 3 + 0] * px + sw1[o * 3 + 1] * py + sw1[o * 3 + 2] * pz;
        s[o >> 3] += a;
        q[o >> 3] += a * a;
    }
    __shared__ float red[4][8][2];
    int wv = threadIdx.x >> 6;
    #pragma unroll
    for (int g = 0; g < 8; g++) {
        float S = s[g], Q = q[g];
        for (int off = 32; off; off >>= 1) {
            S += __shfl_down(S, off, 64);
            Q += __shfl_down(Q, off, 64);
        }
        if ((threadIdx.x & 63) == 0) { red[wv][g][0] = S; red[wv][g][1] = Q; }
    }
    __syncthreads();
    if (threadIdx.x < 8) {
        int g = threadIdx.x;
        float S = red[0][g][0] + red[1][g][0] + red[2][g][0] + red[3][g][0];
        float Q = red[0][g][1] + red[1][g][1] + red[2][g][1] + red[3][g][1];
        float* d = pstat1 + (((size_t)(b * 8 + g)) * 16 + pc) * 2;
        d[0] = S; d[1] = Q;
    }
}

__global__ __launch_bounds__(64) void gn_finalize1(const float* __restrict__ pstat,
                                                   const float* __restrict__ gamma,
                                                   const float* __restrict__ beta,
                                                   float* __restrict__ scale,
                                                   float* __restrict__ shift) {
    int b = blockIdx.x >> 3, g = blockIdx.x & 7;
    const float* base = pstat + (size_t)(b * 8 + g) * 32;
    float S = 0.f, Q = 0.f;
    if (threadIdx.x < 16) { S = base[threadIdx.x * 2]; Q = base[threadIdx.x * 2 + 1]; }
    for (int off = 8; off; off >>= 1) {
        S += __shfl_down(S, off, 64);
        Q += __shfl_down(Q, off, 64);
    }
    __shared__ float ms[2];
    if (threadIdx.x == 0) {
        float inv = 1.0f / (8.0f * 4096.0f);
        float mu = S * inv;
        float var = Q * inv - mu * mu;
        if (var < 0.f) var = 0.f;
        ms[0] = mu; ms[1] = rsqrtf(var + 1e-5f);
    }
    __syncthreads();
    if (threadIdx.x < 8) {
        int c = g * 8 + threadIdx.x;
        float ga = gamma[c] * ms[1];
        scale[b * 64 + c] = ga;
        shift[b * 64 + c] = beta[c] - ms[0] * ga;
    }
}

// ---------------- weight cast: all three weights -> fragment layout, one kernel ----------------
// Wfrag chunk t: lane=t&63, cb=(t>>6)%NCB, ob=t/(64*NCB); o=ob*16+(lane&15), c0=cb*32+(lane>>4)*8

__device__ inline void cast_chunk(const float* __restrict__ wf, _Float16* __restrict__ wh,
                                  int CIN, int t) {
    int lane = t & 63;
    int NCB = CIN / 32;
    int cb = (t >> 6) % NCB;
    int ob = t / (64 * NCB);
    int o = ob * 16 + (lane & 15);
    int c0 = cb * 32 + (lane >> 4) * 8;
    const float* src = wf + (size_t)o * CIN + c0;
    f16x8 v;
    #pragma unroll
    for (int e = 0; e < 8; e++) v[e] = (_Float16)src[e];
    *(f16x8*)(wh + (size_t)t * 8) = v;
}

__global__ __launch_bounds__(256) void cast_w_all(const float* __restrict__ w2,
                                                  const float* __restrict__ w3,
                                                  const float* __restrict__ w4,
                                                  _Float16* __restrict__ w2f,
                                                  _Float16* __restrict__ w3f,
                                                  _Float16* __restrict__ w4f) {
    int t = blockIdx.x * 256 + threadIdx.x;
    if (t < 1024) cast_chunk(w2, w2f, 64, t);
    else if (t < 1024 + 4096) cast_chunk(w3, w3f, 128, t - 1024);
    else if (t < 1024 + 4096 + 16384) cast_chunk(w4, w4f, 256, t - 5120);
}

// ---------------- fused layer 2: conv1+GN+ReLU stage -> GEMM(all O) -> y2 + pstat ----------------
// block: 64-point tile x all 128 outputs. LDS stage then reused for stats.

__global__ __launch_bounds__(256) void fused_l2(const float* __restrict__ pts,
                                                const float* __restrict__ w1,
                                                const float* __restrict__ scale,
                                                const float* __restrict__ shift,
                                                const _Float16* __restrict__ wfrag,
                                                _Float16* __restrict__ yout,
                                                float* __restrict__ pstat) {
    constexpr int CIN = 64, COUT = 128, NCB = 2;
    __shared__ char smem[8192];                 // stage 64*64*2 = 8KB >= sred 4*128*2*4 = 4KB
    __shared__ float sw1[192], ssc[64], ssh[64];
    _Float16* sl = (_Float16*)smem;
    float* sred = (float*)smem;
    int b = blockIdx.y, pblk = blockIdx.x, tid = threadIdx.x;
    int Pg = b * 64 + pblk;
    if (tid < 192) sw1[tid] = w1[tid];
    if (tid < 64) { ssc[tid] = scale[b * 64 + tid]; ssh[tid] = shift[b * 64 + tid]; }
    __syncthreads();
    {   // stage: recompute conv1 + norm + relu -> swizzled LDS
        int p = tid >> 2, qo = (tid & 3) * 16;
        int pg = pblk * 64 + p;
        float x0 = pts[((size_t)b * 3 + 0) * NPTS + pg];
        float x1 = pts[((size_t)b * 3 + 1) * NPTS + pg];
        float x2 = pts[((size_t)b * 3 + 2) * NPTS + pg];
        #pragma unroll
        for (int e = 0; e < 16; e++) {
            int o = qo + e;
            float a = sw1[o * 3 + 0] * x0 + sw1[o * 3 + 1] * x1 + sw1[o * 3 + 2] * x2;
            float r = fmaxf(a * ssc[o] + ssh[o], 0.f);
            int ch = o >> 3;
            sl[p * CIN + ((ch ^ (p & 7)) << 3) + (o & 7)] = (_Float16)r;
        }
    }
    __syncthreads();
    int wv = tid >> 6, lane = tid & 63, lr = lane & 15, lk = lane >> 4;
    int p = wv * 16 + lr;
    f16x8 af[NCB];
    #pragma unroll
    for (int cb = 0; cb < NCB; cb++) {
        int ch = cb * 4 + lk;
        af[cb] = *(const f16x8*)(sl + p * CIN + ((ch ^ (p & 7)) << 3));
    }
    __syncthreads();   // stage dead -> sred live
    #pragma unroll 2
    for (int of = 0; of < COUT / 16; of++) {
        f32x4 acc = {};
        #pragma unroll
        for (int cb = 0; cb < NCB; cb++) {
            f16x8 bf = *(const f16x8*)(wfrag + ((size_t)(of * NCB + cb) * 64 + lane) * 8);
            acc = __builtin_amdgcn_mfma_f32_16x16x32_f16(af[cb], bf, acc, 0, 0, 0);
        }
        f16x4 vv;
        #pragma unroll
        for (int j = 0; j < 4; j++) vv[j] = (_Float16)acc[j];
        *(f16x4*)(yout + ((size_t)Pg * (COUT / 64) + (of >> 2)) * 4096 +
                  (((of & 3) * 4 + wv) * 64 + lane) * 4) = vv;
        float S = acc[0] + acc[1] + acc[2] + acc[3];
        float Q = acc[0] * acc[0] + acc[1] * acc[1] + acc[2] * acc[2] + acc[3] * acc[3];
        S += __shfl_xor(S, 16, 64); Q += __shfl_xor(Q, 16, 64);
        S += __shfl_xor(S, 32, 64); Q += __shfl_xor(Q, 32, 64);
        if (lk == 0) {
            float* d = sred + ((size_t)(wv * COUT + of * 16 + lr)) * 2;
            d[0] = S; d[1] = Q;
        }
    }
    __syncthreads();
    for (int o = tid; o < COUT; o += 256) {
        float S = 0.f, Q = 0.f;
        #pragma unroll
        for (int w = 0; w < 4; w++) {
            const float* d = sred + ((size_t)(w * COUT + o)) * 2;
            S += d[0]; Q += d[1];
        }
        float* d = pstat + (((size_t)(b * 64 + pblk)) * COUT + o) * 2;
        d[0] = S; d[1] = Q;
    }
}

// ---------------- fused layer (3,4): D-read stage -> GEMM(all O) -> y/pool + pstat ----------------

template <int CIN, int COUT, bool POOL>
__global__ __launch_bounds__(256) void fused_layer(const _Float16* __restrict__ yprev,
                                                   const float* __restrict__ scale,
                                                   const float* __restrict__ shift,
                                                   const _Float16* __restrict__ wfrag,
                                                   _Float16* __restrict__ yout,
                                                   float* __restrict__ pstat) {
    constexpr int NCB = CIN / 32;
    constexpr int NST = POOL ? 4 : 2;
    constexpr int STAGE_B = 64 * CIN * 2;
    constexpr int SRED_B = 4 * COUT * NST * 4;
    constexpr int UNION_B = STAGE_B > SRED_B ? STAGE_B : SRED_B;
    __shared__ char smem[UNION_B];
    __shared__ float ssc[CIN], ssh[CIN];
    _Float16* sl = (_Float16*)smem;
    float* sred = (float*)smem;
    int b = blockIdx.y, pblk = blockIdx.x, tid = threadIdx.x;
    int Pg = b * 64 + pblk;
    for (int i = tid; i < CIN; i += 256) { ssc[i] = scale[b * CIN + i]; ssh[i] = shift[b * CIN + i]; }
    __syncthreads();
    // stage: D-native tile -> norm+relu -> swizzled LDS
    const _Float16* yt = yprev + (size_t)Pg * 64 * CIN;
    constexpr int NCH4 = 64 * CIN / 4;
    for (int q = tid; q < NCH4; q += 256) {
        int lane = q & 63;
        int pf = (q >> 6) & 3;
        int ofi = (q >> 8) & 3;
        int Ob = q >> 10;
        int o = Ob * 64 + ofi * 16 + (lane & 15);
        int pbase = pf * 16 + (lane >> 4) * 4;
        f16x4 v = *(const f16x4*)(yt + (size_t)q * 4);
        float sc = ssc[o], sh = ssh[o];
        int ch = o >> 3;
        #pragma unroll
        for (int e = 0; e < 4; e++) {
            int p = pbase + e;
            float r = fmaxf((float)v[e] * sc + sh, 0.f);
            sl[p * CIN + ((ch ^ (p & 7)) << 3) + (o & 7)] = (_Float16)r;
        }
    }
    __syncthreads();
    int wv = tid >> 6, lane = tid & 63, lr = lane & 15, lk = lane >> 4;
    int p = wv * 16 + lr;
    f16x8 af[NCB];
    #pragma unroll
    for (int cb = 0; cb < NCB; cb++) {
        int ch = cb * 4 + lk;
        af[cb] = *(const f16x8*)(sl + p * CIN + ((ch ^ (p & 7)) << 3));
    }
    __syncthreads();   // stage dead -> sred live
    #pragma unroll 2
    for (int of = 0; of < COUT / 16; of++) {
        f32x4 acc = {};
        #pragma unroll
        for (int cb = 0; cb < NCB; cb++) {
            f16x8 bf = *(const f16x8*)(wfrag + ((size_t)(of * NCB + cb) * 64 + lane) * 8);
            acc = __builtin_amdgcn_mfma_f32_16x16x32_f16(af[cb], bf, acc, 0, 0, 0);
        }
        if (!POOL) {
            f16x4 vv;
            #pragma unroll
            for (int j = 0; j < 4; j++) vv[j] = (_Float16)acc[j];
            *(f16x4*)(yout + ((size_t)Pg * (COUT / 64) + (of >> 2)) * 4096 +
                      (((of & 3) * 4 + wv) * 64 + lane) * 4) = vv;
        }
        float S = acc[0] + acc[1] + acc[2] + acc[3];
        float Q = acc[0] * acc[0] + acc[1] * acc[1] + acc[2] * acc[2] + acc[3] * acc[3];
        float MX = 0.f, MN = 0.f;
        if (POOL) {
            MX = fmaxf(fmaxf(acc[0], acc[1]), fmaxf(acc[2], acc[3]));
            MN = fminf(fminf(acc[0], acc[1]), fminf(acc[2], acc[3]));
        }
        S += __shfl_xor(S, 16, 64); Q += __shfl_xor(Q, 16, 64);
        S += __shfl_xor(S, 32, 64); Q += __shfl_xor(Q, 32, 64);
        if (POOL) {
            MX = fmaxf(MX, __shfl_xor(MX, 16, 64)); MN = fminf(MN, __shfl_xor(MN, 16, 64));
            MX = fmaxf(MX, __shfl_xor(MX, 32, 64)); MN = fminf(MN, __shfl_xor(MN, 32, 64));
        }
        if (lk == 0) {
            float* d = sred + ((size_t)(wv * COUT + of * 16 + lr)) * NST;
            d[0] = S; d[1] = Q;
            if (POOL) { d[2] = MX; d[3] = MN; }
        }
    }
    __syncthreads();
    for (int o = tid; o < COUT; o += 256) {
        float S = 0.f, Q = 0.f, MX = -1e30f, MN = 1e30f;
        #pragma unroll
        for (int w = 0; w < 4; w++) {
            const float* d = sred + ((size_t)(w * COUT + o)) * NST;
            S += d[0]; Q += d[1];
            if (POOL) { MX = fmaxf(MX, d[2]); MN = fminf(MN, d[3]); }
        }
        float* d = pstat + (((size_t)(b * 64 + pblk)) * COUT + o) * NST;
        if (POOL) *(float4*)d = make_float4(S, Q, MX, MN);
        else { d[0] = S; d[1] = Q; }
    }
}

// ---------------- GN finalize (layers 2,3): pstat[b][64][C][2] -> scale/shift ----------------

template <int C>
__global__ __launch_bounds__(256) void gn_finalizeG(const float* __restrict__ pstat,
                                                    const float* __restrict__ gamma,
                                                    const float* __restrict__ beta,
                                                    float* __restrict__ scale,
                                                    float* __restrict__ shift) {
    constexpr int GS = C / 8;
    int b = blockIdx.x >> 3, g = blockIdx.x & 7;
    const float* base = pstat + (size_t)b * 64 * C * 2;
    float S = 0.f, Q = 0.f;
    for (int i = threadIdx.x; i < 64 * GS; i += 256) {
        int pb = i / GS;
        int c = g * GS + (i % GS);
        const float* d = base + ((size_t)pb * C + c) * 2;
        S += d[0]; Q += d[1];
    }
    for (int off = 32; off; off >>= 1) {
        S += __shfl_down(S, off, 64);
        Q += __shfl_down(Q, off, 64);
    }
    __shared__ float ss[8];
    if ((threadIdx.x & 63) == 0) {
        ss[(threadIdx.x >> 6) * 2] = S;
        ss[(threadIdx.x >> 6) * 2 + 1] = Q;
    }
    __syncthreads();
    __shared__ float ms[2];
    if (threadIdx.x == 0) {
        float St = ss[0] + ss[2] + ss[4] + ss[6];
        float Qt = ss[1] + ss[3] + ss[5] + ss[7];
        float inv = 1.0f / ((float)GS * 4096.0f);
        float mu = St * inv;
        float var = Qt * inv - mu * mu;
        if (var < 0.f) var = 0.f;
        ms[0] = mu; ms[1] = rsqrtf(var + 1e-5f);
    }
    __syncthreads();
    for (int i = threadIdx.x; i < GS; i += 256) {
        int c = g * GS + i;
        float ga = gamma[c] * ms[1];
        scale[(size_t)b * C + c] = ga;
        shift[(size_t)b * C + c] = beta[c] - ms[0] * ga;
    }
}

// ---------------- pool finalize: pstat4[b][64][512][4] -> g[b][512] ----------------

__global__ __launch_bounds__(256) void pool_final(const float* __restrict__ pstat4,
                                                  const float* __restrict__ gamma,
                                                  const float* __restrict__ beta,
                                                  float* __restrict__ g) {
    int b = blockIdx.x;
    __shared__ float sS[512], sQ[512];
    __shared__ float ms[8][2];
    float MXa[2], MNa[2];
    #pragma unroll
    for (int h = 0; h < 2; h++) {
        int o = threadIdx.x + h * 256;
        float S = 0.f, Q = 0.f, MX = -1e30f, MN = 1e30f;
        for (int pb = 0; pb < 64; pb++) {
            float4 v = *(const float4*)(pstat4 + (((size_t)(b * 64 + pb)) * 512 + o) * 4);
            S += v.x; Q += v.y; MX = fmaxf(MX, v.z); MN = fminf(MN, v.w);
        }
        MXa[h] = MX; MNa[h] = MN;
        sS[o] = S; sQ[o] = Q;
    }
    __syncthreads();
    if (threadIdx.x < 8) {
        int gr = threadIdx.x;
        float St = 0.f, Qt = 0.f;
        for (int i = 0; i < 64; i++) { St += sS[gr * 64 + i]; Qt += sQ[gr * 64 + i]; }
        float inv = 1.0f / (64.0f * 4096.0f);
        float mu = St * inv;
        float var = Qt * inv - mu * mu;
        if (var < 0.f) var = 0.f;
        ms[gr][0] = mu; ms[gr][1] = rsqrtf(var + 1e-5f);
    }
    __syncthreads();
    #pragma unroll
    for (int h = 0; h < 2; h++) {
        int o = threadIdx.x + h * 256;
        int gr = o >> 6;
        float sc = gamma[o] * ms[gr][1];
        float sh = beta[o] - ms[gr][0] * sc;
        float m = (sc >= 0.f ? MXa[h] : MNa[h]) * sc + sh;
        g[b * 512 + o] = fmaxf(m, 0.f);
    }
}

// ---------------- FC head ----------------

__global__ __launch_bounds__(128) void head_kernel(const float* __restrict__ g,
                                                   const float* __restrict__ fc1w,
                                                   const float* __restrict__ fc1b,
                                                   const float* __restrict__ fc2w,
                                                   const float* __restrict__ fc2b,
                                                   float* __restrict__ out) {
    int b = blockIdx.x;
    int o = threadIdx.x;   // 128
    __shared__ float sg[512];
    for (int i = threadIdx.x; i < 512; i += 128) sg[i] = g[b * 512 + i];
    __syncthreads();
    float acc = fc1b[o];
    for (int c = 0; c < 512; c++) acc += sg[c] * fc1w[o * 512 + c];
    float h = fmaxf(acc, 0.f) * fc2w[o];
    for (int off = 32; off; off >>= 1) h += __shfl_down(h, off, 64);
    __shared__ float s2[2];
    if ((threadIdx.x & 63) == 0) s2[threadIdx.x >> 6] = h;
    __syncthreads();
    if (threadIdx.x == 0) out[b] = s2[0] + s2[1] + fc2b[0];
}

// ---------------- launch ----------------

extern "C" void kernel_launch(void* const* d_in, const int* in_sizes, int n_in,
                              void* d_out, int out_size, void* d_ws, size_t ws_size,
                              hipStream_t stream) {
    const float* vol  = (const float*)d_in[0];
    const float* w1   = (const float*)d_in[1];
    const float* gn1w = (const float*)d_in[2];
    const float* gn1b = (const float*)d_in[3];
    const float* w2   = (const float*)d_in[4];
    const float* gn2w = (const float*)d_in[5];
    const float* gn2b = (const float*)d_in[6];
    const float* w3   = (const float*)d_in[7];
    const float* gn3w = (const float*)d_in[8];
    const float* gn3b = (const float*)d_in[9];
    const float* w4   = (const float*)d_in[10];
    const float* gn4w = (const float*)d_in[11];
    const float* gn4b = (const float*)d_in[12];
    const float* fc1w = (const float*)d_in[13];
    const float* fc1b = (const float*)d_in[14];
    const float* fc2w = (const float*)d_in[15];
    const float* fc2b = (const float*)d_in[16];
    float* out = (float*)d_out;

    char* ws = (char*)d_ws;
    size_t cur = 0;
    auto alloc = [&](size_t bytes) -> void* {
        cur = (cur + 255) & ~(size_t)255;
        void* p = ws + cur;
        cur += bytes;
        return p;
    };
    int*      counts  = (int*)alloc((size_t)NB * NCHUNK * 4);
    int*      prefix  = (int*)alloc((size_t)NB * NCHUNK * 4);
    int*      totals  = (int*)alloc(64);
    unsigned long long* bits = (unsigned long long*)alloc((size_t)NB * NCHUNK * 16 * 8);
    float*    pts     = (float*)alloc((size_t)NB * 3 * NPTS * 4);
    float*    gbuf    = (float*)alloc((size_t)NB * 512 * 4);
    float*    pstat1  = (float*)alloc((size_t)NB * 8 * 16 * 2 * 4);
    float*    pstatG  = (float*)alloc((size_t)NB * 64 * 256 * 2 * 4);
    float*    pstat4  = (float*)alloc((size_t)NB * 64 * 512 * 4 * 4);
    float*    scale   = (float*)alloc((size_t)NB * 512 * 4);
    float*    shift   = (float*)alloc((size_t)NB * 512 * 4);
    _Float16* w2f     = (_Float16*)alloc((size_t)128 * 64 * 2);
    _Float16* w3f     = (_Float16*)alloc((size_t)256 * 128 * 2);
    _Float16* w4f     = (_Float16*)alloc((size_t)512 * 256 * 2);
    _Float16* y2      = (_Float16*)alloc((size_t)NB * NPTS * 128 * 2);
    _Float16* y3      = (_Float16*)alloc((size_t)NB * NPTS * 256 * 2);

    // 1. mask/count/scan, then points + fused conv1 stats
    count_kernel<<<dim3(NB * NCHUNK), dim3(256), 0, stream>>>(vol, counts, bits);
    scan_kernel<<<dim3(NB), dim3(1024), 0, stream>>>(counts, prefix, totals);
    points_kernel<<<dim3(NB * 16), dim3(256), 0, stream>>>(bits, prefix, totals, w1, pts, pstat1);

    // 2. weight casts (one kernel)
    cast_w_all<<<dim3(84), dim3(256), 0, stream>>>(w2, w3, w4, w2f, w3f, w4f);

    // 3. layer-1 finalize, then fused layer 2 (conv1 recompute + GEMM)
    gn_finalize1<<<dim3(NB * 8), dim3(64), 0, stream>>>(pstat1, gn1w, gn1b, scale, shift);
    fused_l2<<<dim3(64, NB), dim3(256), 0, stream>>>(pts, w1, scale, shift, w2f, y2, pstatG);

    // 4. layer 3
    gn_finalizeG<128><<<dim3(NB * 8), dim3(256), 0, stream>>>(pstatG, gn2w, gn2b, scale, shift);
    fused_layer<128, 256, false><<<dim3(64, NB), dim3(256), 0, stream>>>(y2, scale, shift, w3f, y3, pstatG);

    // 5. layer 4 (pooled epilogue, no y4)
    gn_finalizeG<256><<<dim3(NB * 8), dim3(256), 0, stream>>>(pstatG, gn3w, gn3b, scale, shift);
    fused_layer<256, 512, true><<<dim3(64, NB), dim3(256), 0, stream>>>(y3, scale, shift, w4f, nullptr, pstat4);

    // 6. pool finalize + head
    pool_final<<<dim3(NB), dim3(256), 0, stream>>>(pstat4, gn4w, gn4b, gbuf);
    head_kernel<<<dim3(NB), dim3(128), 0, stream>>>(gbuf, fc1w, fc1b, fc2w, fc2b, out);
}

// Round 7
// 126.024 us; speedup vs baseline: 1.1079x; 1.1079x over previous
//
#include <hip/hip_runtime.h>
#include <hip/hip_bf16.h>

#define NB 16
#define VOX 884736        // 96*96*96
#define NPTS 4096
#define CHUNK 1024
#define NCHUNK 864        // VOX / CHUNK

typedef _Float16 f16x8 __attribute__((ext_vector_type(8)));
typedef _Float16 f16x4 __attribute__((ext_vector_type(4)));
typedef float f32x4 __attribute__((ext_vector_type(4)));

// ---------------- count + bitmask ----------------

__global__ __launch_bounds__(256) void count_kernel(const float* __restrict__ vol,
                                                    int* __restrict__ counts,
                                                    unsigned long long* __restrict__ bits) {
    int blk = blockIdx.x;  // b*NCHUNK + c
    const float4* v4 = (const float4*)(vol + (size_t)blk * CHUNK);
    float4 v = v4[threadIdx.x];
    int nib = (v.x > 0.5f) | ((v.y > 0.5f) << 1) | ((v.z > 0.5f) << 2) | ((v.w > 0.5f) << 3);
    __shared__ unsigned char nibs[256];
    nibs[threadIdx.x] = (unsigned char)nib;
    int cnt = __popc(nib);
    for (int off = 32; off; off >>= 1) cnt += __shfl_down(cnt, off, 64);
    __shared__ int s[4];
    if ((threadIdx.x & 63) == 0) s[threadIdx.x >> 6] = cnt;
    __syncthreads();
    if (threadIdx.x < 16) {
        unsigned long long wd = 0;
        #pragma unroll
        for (int i = 0; i < 16; i++)
            wd |= (unsigned long long)nibs[threadIdx.x * 16 + i] << (4 * i);
        bits[(size_t)blk * 16 + threadIdx.x] = wd;
    }
    if (threadIdx.x == 0) counts[blk] = s[0] + s[1] + s[2] + s[3];
}

__global__ __launch_bounds__(1024) void scan_kernel(const int* __restrict__ counts,
                                                    int* __restrict__ prefix,
                                                    int* __restrict__ totals) {
    __shared__ int s[1024];
    int b = blockIdx.x, t = threadIdx.x;
    int v = (t < NCHUNK) ? counts[b * NCHUNK + t] : 0;
    s[t] = v;
    __syncthreads();
    for (int off = 1; off < 1024; off <<= 1) {
        int x = (t >= off) ? s[t - off] : 0;
        __syncthreads();
        s[t] += x;
        __syncthreads();
    }
    if (t < NCHUNK) prefix[b * NCHUNK + t] = s[t] - v;   // exclusive
    if (t == NCHUNK - 1) totals[b] = s[t];
}

// ---------------- points via bitmask rank-select, fused conv1 stats ----------------

__global__ __launch_bounds__(256) void points_kernel(const unsigned long long* __restrict__ bits,
                                                     const int* __restrict__ prefix,
                                                     const int* __restrict__ totals,
                                                     const float* __restrict__ w1,
                                                     float* __restrict__ pts,
                                                     float* __restrict__ pstat1) {
    int b = blockIdx.x >> 4;
    int pc = blockIdx.x & 15;
    int p = pc * 256 + threadIdx.x;
    __shared__ int spref[NCHUNK];
    __shared__ float sw1[192];
    for (int i = threadIdx.x; i < NCHUNK; i += 256) spref[i] = prefix[b * NCHUNK + i];
    if (threadIdx.x < 192) sw1[threadIdx.x] = w1[threadIdx.x];
    __syncthreads();
    int n = totals[b];
    float px = 0.f, py = 0.f, pz = 0.f;
    if (n > 0) {
        int k;
        if (n >= NPTS) {
            float t = (float)p * ((float)n - 1.0f);
            t = t / 4095.0f;
            k = (int)t;
            if (k > n - 1) k = n - 1;
            if (k < 0) k = 0;
        } else {
            k = p % n;
        }
        int lo = 0, hi = NCHUNK - 1;
        while (lo < hi) {
            int mid = (lo + hi + 1) >> 1;
            if (spref[mid] <= k) lo = mid; else hi = mid - 1;
        }
        int rr = k - spref[lo];
        const unsigned long long* wb = bits + ((size_t)b * NCHUNK + lo) * 16;
        unsigned long long chosen = 0;
        int wordidx = 0;
        bool found = false;
        #pragma unroll
        for (int w = 0; w < 16; w++) {
            unsigned long long m = wb[w];
            int pcnt = __popcll(m);
            bool take = (!found) && (rr < pcnt);
            if (take) { chosen = m; wordidx = w; found = true; }
            if (!found) rr -= pcnt;
        }
        int pos = 0;
        unsigned long long m64 = chosen;
        int c = __popcll(m64 & 0xFFFFFFFFull);
        if (rr >= c) { pos = 32; rr -= c; m64 >>= 32; }
        unsigned mm = (unsigned)m64;
        c = __popc(mm & 0xFFFFu); if (rr >= c) { pos += 16; rr -= c; mm >>= 16; }
        c = __popc(mm & 0xFFu);   if (rr >= c) { pos += 8;  rr -= c; mm >>= 8; }
        c = __popc(mm & 0xFu);    if (rr >= c) { pos += 4;  rr -= c; mm >>= 4; }
        c = __popc(mm & 0x3u);    if (rr >= c) { pos += 2;  rr -= c; mm >>= 2; }
        c = mm & 1u;              if (rr >= c) { pos += 1; }
        int flat = lo * CHUNK + wordidx * 64 + pos;
        int dd = flat / 9216;           // 96*96
        int rem = flat - dd * 9216;
        int hh = rem / 96;
        int ww = rem - hh * 96;
        px = (float)dd / 95.0f * 2.0f - 1.0f;
        py = (float)hh / 95.0f * 2.0f - 1.0f;
        pz = (float)ww / 95.0f * 2.0f - 1.0f;
    }
    pts[((size_t)b * 3 + 0) * NPTS + p] = px;
    pts[((size_t)b * 3 + 1) * NPTS + p] = py;
    pts[((size_t)b * 3 + 2) * NPTS + p] = pz;
    // fused conv1 GN partial stats
    float s[8] = {}, q[8] = {};
    #pragma unroll
    for (int o = 0; o < 64; o++) {
        float a = sw1[o * 3 + 0] * px + sw1[o * 3 + 1] * py + sw1[o * 3 + 2] * pz;
        s[o >> 3] += a;
        q[o >> 3] += a * a;
    }
    __shared__ float red[4][8][2];
    int wv = threadIdx.x >> 6;
    #pragma unroll
    for (int g = 0; g < 8; g++) {
        float S = s[g], Q = q[g];
        for (int off = 32; off; off >>= 1) {
            S += __shfl_down(S, off, 64);
            Q += __shfl_down(Q, off, 64);
        }
        if ((threadIdx.x & 63) == 0) { red[wv][g][0] = S; red[wv][g][1] = Q; }
    }
    __syncthreads();
    if (threadIdx.x < 8) {
        int g = threadIdx.x;
        float S = red[0][g][0] + red[1][g][0] + red[2][g][0] + red[3][g][0];
        float Q = red[0][g][1] + red[1][g][1] + red[2][g][1] + red[3][g][1];
        float* d = pstat1 + (((size_t)(b * 8 + g)) * 16 + pc) * 2;
        d[0] = S; d[1] = Q;
    }
}

__global__ __launch_bounds__(64) void gn_finalize1(const float* __restrict__ pstat,
                                                   const float* __restrict__ gamma,
                                                   const float* __restrict__ beta,
                                                   float* __restrict__ scale,
                                                   float* __restrict__ shift) {
    int b = blockIdx.x >> 3, g = blockIdx.x & 7;
    const float* base = pstat + (size_t)(b * 8 + g) * 32;
    float S = 0.f, Q = 0.f;
    if (threadIdx.x < 16) { S = base[threadIdx.x * 2]; Q = base[threadIdx.x * 2 + 1]; }
    for (int off = 8; off; off >>= 1) {
        S += __shfl_down(S, off, 64);
        Q += __shfl_down(Q, off, 64);
    }
    __shared__ float ms[2];
    if (threadIdx.x == 0) {
        float inv = 1.0f / (8.0f * 4096.0f);
        float mu = S * inv;
        float var = Q * inv - mu * mu;
        if (var < 0.f) var = 0.f;
        ms[0] = mu; ms[1] = rsqrtf(var + 1e-5f);
    }
    __syncthreads();
    if (threadIdx.x < 8) {
        int c = g * 8 + threadIdx.x;
        float ga = gamma[c] * ms[1];
        scale[b * 64 + c] = ga;
        shift[b * 64 + c] = beta[c] - ms[0] * ga;
    }
}

// ---------------- weight cast: all three -> fragment layout ----------------

__device__ inline void cast_chunk(const float* __restrict__ wf, _Float16* __restrict__ wh,
                                  int CIN, int t) {
    int lane = t & 63;
    int NCB = CIN / 32;
    int cb = (t >> 6) % NCB;
    int ob = t / (64 * NCB);
    int o = ob * 16 + (lane & 15);
    int c0 = cb * 32 + (lane >> 4) * 8;
    const float* src = wf + (size_t)o * CIN + c0;
    f16x8 v;
    #pragma unroll
    for (int e = 0; e < 8; e++) v[e] = (_Float16)src[e];
    *(f16x8*)(wh + (size_t)t * 8) = v;
}

__global__ __launch_bounds__(256) void cast_w_all(const float* __restrict__ w2,
                                                  const float* __restrict__ w3,
                                                  const float* __restrict__ w4,
                                                  _Float16* __restrict__ w2f,
                                                  _Float16* __restrict__ w3f,
                                                  _Float16* __restrict__ w4f) {
    int t = blockIdx.x * 256 + threadIdx.x;
    if (t < 1024) cast_chunk(w2, w2f, 64, t);
    else if (t < 1024 + 4096) cast_chunk(w3, w3f, 128, t - 1024);
    else if (t < 1024 + 4096 + 16384) cast_chunk(w4, w4f, 256, t - 5120);
}

// ---------------- GEMM core: wave owns 64 points x COUT/4 channels, 4xCOF reg tile ----------------
// sl: staged 64 x CIN fp16 tile, XOR-swizzled. pstat written straight from registers.

template <int CIN, int COUT, bool POOL>
__device__ __forceinline__ void gemm_core(const _Float16* __restrict__ sl,
                                          const _Float16* __restrict__ wfrag,
                                          _Float16* __restrict__ yout,
                                          float* __restrict__ pstat,
                                          int b, int pblk, int tid) {
    constexpr int NCB = CIN / 32;
    constexpr int OFW = COUT / 64;          // of-frags per wave
    constexpr int COF = OFW > 4 ? 4 : OFW;  // chunk of of-frags
    constexpr int NCHK = OFW / COF;
    int wv = tid >> 6, lane = tid & 63, lr = lane & 15, lk = lane >> 4;
    int Pg = b * 64 + pblk;
    #pragma unroll
    for (int ck = 0; ck < NCHK; ck++) {
        f32x4 acc[4][COF] = {};
        #pragma unroll
        for (int cb = 0; cb < NCB; cb++) {
            f16x8 af[4];
            int ch = cb * 4 + lk;
            #pragma unroll
            for (int pf = 0; pf < 4; pf++) {
                int p = pf * 16 + lr;
                af[pf] = *(const f16x8*)(sl + p * CIN + ((ch ^ (p & 7)) << 3));
            }
            f16x8 bf[COF];
            #pragma unroll
            for (int i = 0; i < COF; i++) {
                int ofr = wv * OFW + ck * COF + i;
                bf[i] = *(const f16x8*)(wfrag + ((size_t)(ofr * NCB + cb) * 64 + lane) * 8);
            }
            #pragma unroll
            for (int pf = 0; pf < 4; pf++)
                #pragma unroll
                for (int i = 0; i < COF; i++)
                    acc[pf][i] = __builtin_amdgcn_mfma_f32_16x16x32_f16(af[pf], bf[i], acc[pf][i], 0, 0, 0);
        }
        #pragma unroll
        for (int i = 0; i < COF; i++) {
            int ofr = wv * OFW + ck * COF + i;
            if (!POOL) {
                _Float16* ytO = yout + ((size_t)Pg * (COUT / 64) + (ofr >> 2)) * 4096;
                #pragma unroll
                for (int pf = 0; pf < 4; pf++) {
                    f16x4 vv;
                    #pragma unroll
                    for (int j = 0; j < 4; j++) vv[j] = (_Float16)acc[pf][i][j];
                    *(f16x4*)(ytO + (((ofr & 3) * 4 + pf) * 64 + lane) * 4) = vv;
                }
            }
            float S = 0.f, Q = 0.f, MX = -1e30f, MN = 1e30f;
            #pragma unroll
            for (int pf = 0; pf < 4; pf++)
                #pragma unroll
                for (int j = 0; j < 4; j++) {
                    float v = acc[pf][i][j];
                    S += v; Q += v * v;
                    if (POOL) { MX = fmaxf(MX, v); MN = fminf(MN, v); }
                }
            S += __shfl_xor(S, 16, 64); Q += __shfl_xor(Q, 16, 64);
            S += __shfl_xor(S, 32, 64); Q += __shfl_xor(Q, 32, 64);
            if (POOL) {
                MX = fmaxf(MX, __shfl_xor(MX, 16, 64)); MN = fminf(MN, __shfl_xor(MN, 16, 64));
                MX = fmaxf(MX, __shfl_xor(MX, 32, 64)); MN = fminf(MN, __shfl_xor(MN, 32, 64));
            }
            if (lk == 0) {
                int o = ofr * 16 + lr;
                if (POOL) {
                    *(float4*)(pstat + ((size_t)Pg * COUT + o) * 4) = make_float4(S, Q, MX, MN);
                } else {
                    float* d = pstat + ((size_t)Pg * COUT + o) * 2;
                    d[0] = S; d[1] = Q;
                }
            }
        }
    }
}

// ---------------- fused layer 2: conv1+GN+ReLU stage -> GEMM ----------------

__global__ __launch_bounds__(256) void fused_l2(const float* __restrict__ pts,
                                                const float* __restrict__ w1,
                                                const float* __restrict__ scale,
                                                const float* __restrict__ shift,
                                                const _Float16* __restrict__ wfrag,
                                                _Float16* __restrict__ yout,
                                                float* __restrict__ pstat) {
    __shared__ _Float16 sl[64 * 64];
    __shared__ float sw1[192], ssc[64], ssh[64];
    int b = blockIdx.y, pblk = blockIdx.x, tid = threadIdx.x;
    if (tid < 192) sw1[tid] = w1[tid];
    if (tid < 64) { ssc[tid] = scale[b * 64 + tid]; ssh[tid] = shift[b * 64 + tid]; }
    __syncthreads();
    {   // stage: recompute conv1 + norm + relu -> swizzled LDS
        int p = tid >> 2, qo = (tid & 3) * 16;
        int pg = pblk * 64 + p;
        float x0 = pts[((size_t)b * 3 + 0) * NPTS + pg];
        float x1 = pts[((size_t)b * 3 + 1) * NPTS + pg];
        float x2 = pts[((size_t)b * 3 + 2) * NPTS + pg];
        #pragma unroll
        for (int e = 0; e < 16; e++) {
            int o = qo + e;
            float a = sw1[o * 3 + 0] * x0 + sw1[o * 3 + 1] * x1 + sw1[o * 3 + 2] * x2;
            float r = fmaxf(a * ssc[o] + ssh[o], 0.f);
            sl[p * 64 + (((o >> 3) ^ (p & 7)) << 3) + (o & 7)] = (_Float16)r;
        }
    }
    __syncthreads();
    gemm_core<64, 128, false>(sl, wfrag, yout, pstat, b, pblk, tid);
}

// ---------------- fused layers 3,4: D-native stage -> GEMM ----------------

template <int CIN, int COUT, bool POOL>
__global__ __launch_bounds__(256) void fused_layer(const _Float16* __restrict__ yprev,
                                                   const float* __restrict__ scale,
                                                   const float* __restrict__ shift,
                                                   const _Float16* __restrict__ wfrag,
                                                   _Float16* __restrict__ yout,
                                                   float* __restrict__ pstat) {
    __shared__ _Float16 sl[64 * CIN];
    __shared__ float ssc[CIN], ssh[CIN];
    int b = blockIdx.y, pblk = blockIdx.x, tid = threadIdx.x;
    int Pg = b * 64 + pblk;
    for (int i = tid; i < CIN; i += 256) { ssc[i] = scale[b * CIN + i]; ssh[i] = shift[b * CIN + i]; }
    __syncthreads();
    const _Float16* yt = yprev + (size_t)Pg * 64 * CIN;
    constexpr int NCH4 = 64 * CIN / 4;
    for (int q = tid; q < NCH4; q += 256) {
        int lane = q & 63;
        int pf = (q >> 6) & 3;
        int ofi = (q >> 8) & 3;
        int Ob = q >> 10;
        int o = Ob * 64 + ofi * 16 + (lane & 15);
        int pbase = pf * 16 + (lane >> 4) * 4;
        f16x4 v = *(const f16x4*)(yt + (size_t)q * 4);
        float sc = ssc[o], sh = ssh[o];
        int ch = o >> 3;
        #pragma unroll
        for (int e = 0; e < 4; e++) {
            int p = pbase + e;
            float r = fmaxf((float)v[e] * sc + sh, 0.f);
            sl[p * CIN + ((ch ^ (p & 7)) << 3) + (o & 7)] = (_Float16)r;
        }
    }
    __syncthreads();
    gemm_core<CIN, COUT, POOL>(sl, wfrag, yout, pstat, b, pblk, tid);
}

// ---------------- GN finalize (layers 2,3): pstat[b][64][C][2] -> scale/shift ----------------

template <int C>
__global__ __launch_bounds__(256) void gn_finalizeG(const float* __restrict__ pstat,
                                                    const float* __restrict__ gamma,
                                                    const float* __restrict__ beta,
                                                    float* __restrict__ scale,
                                                    float* __restrict__ shift) {
    constexpr int GS = C / 8;
    int b = blockIdx.x >> 3, g = blockIdx.x & 7;
    const float* base = pstat + (size_t)b * 64 * C * 2;
    float S = 0.f, Q = 0.f;
    for (int i = threadIdx.x; i < 64 * GS; i += 256) {
        int pb = i / GS;
        int c = g * GS + (i % GS);
        const float* d = base + ((size_t)pb * C + c) * 2;
        S += d[0]; Q += d[1];
    }
    for (int off = 32; off; off >>= 1) {
        S += __shfl_down(S, off, 64);
        Q += __shfl_down(Q, off, 64);
    }
    __shared__ float ss[8];
    if ((threadIdx.x & 63) == 0) {
        ss[(threadIdx.x >> 6) * 2] = S;
        ss[(threadIdx.x >> 6) * 2 + 1] = Q;
    }
    __syncthreads();
    __shared__ float ms[2];
    if (threadIdx.x == 0) {
        float St = ss[0] + ss[2] + ss[4] + ss[6];
        float Qt = ss[1] + ss[3] + ss[5] + ss[7];
        float inv = 1.0f / ((float)GS * 4096.0f);
        float mu = St * inv;
        float var = Qt * inv - mu * mu;
        if (var < 0.f) var = 0.f;
        ms[0] = mu; ms[1] = rsqrtf(var + 1e-5f);
    }
    __syncthreads();
    for (int i = threadIdx.x; i < GS; i += 256) {
        int c = g * GS + i;
        float ga = gamma[c] * ms[1];
        scale[(size_t)b * C + c] = ga;
        shift[(size_t)b * C + c] = beta[c] - ms[0] * ga;
    }
}

// ---------------- pool finalize: one wave per (b, group) ----------------

__global__ __launch_bounds__(64) void pool_final(const float* __restrict__ pstat4,
                                                 const float* __restrict__ gamma,
                                                 const float* __restrict__ beta,
                                                 float* __restrict__ g) {
    int b = blockIdx.x >> 3, gr = blockIdx.x & 7;
    int o = gr * 64 + threadIdx.x;
    float S = 0.f, Q = 0.f, MX = -1e30f, MN = 1e30f;
    for (int pb = 0; pb < 64; pb++) {
        float4 v = *(const float4*)(pstat4 + (((size_t)(b * 64 + pb)) * 512 + o) * 4);
        S += v.x; Q += v.y; MX = fmaxf(MX, v.z); MN = fminf(MN, v.w);
    }
    float St = S, Qt = Q;
    for (int off = 32; off; off >>= 1) {
        St += __shfl_xor(St, off, 64);
        Qt += __shfl_xor(Qt, off, 64);
    }
    float inv = 1.0f / (64.0f * 4096.0f);
    float mu = St * inv;
    float var = Qt * inv - mu * mu;
    if (var < 0.f) var = 0.f;
    float rstd = rsqrtf(var + 1e-5f);
    float sc = gamma[o] * rstd;
    float sh = beta[o] - mu * sc;
    float m = (sc >= 0.f ? MX : MN) * sc + sh;
    g[b * 512 + o] = fmaxf(m, 0.f);
}

// ---------------- FC head ----------------

__global__ __launch_bounds__(128) void head_kernel(const float* __restrict__ g,
                                                   const float* __restrict__ fc1w,
                                                   const float* __restrict__ fc1b,
                                                   const float* __restrict__ fc2w,
                                                   const float* __restrict__ fc2b,
                                                   float* __restrict__ out) {
    int b = blockIdx.x;
    int o = threadIdx.x;   // 128
    __shared__ float sg[512];
    for (int i = threadIdx.x; i < 512; i += 128) sg[i] = g[b * 512 + i];
    __syncthreads();
    float acc = fc1b[o];
    for (int c = 0; c < 512; c++) acc += sg[c] * fc1w[o * 512 + c];
    float h = fmaxf(acc, 0.f) * fc2w[o];
    for (int off = 32; off; off >>= 1) h += __shfl_down(h, off, 64);
    __shared__ float s2[2];
    if ((threadIdx.x & 63) == 0) s2[threadIdx.x >> 6] = h;
    __syncthreads();
    if (threadIdx.x == 0) out[b] = s2[0] + s2[1] + fc2b[0];
}

// ---------------- launch ----------------

extern "C" void kernel_launch(void* const* d_in, const int* in_sizes, int n_in,
                              void* d_out, int out_size, void* d_ws, size_t ws_size,
                              hipStream_t stream) {
    const float* vol  = (const float*)d_in[0];
    const float* w1   = (const float*)d_in[1];
    const float* gn1w = (const float*)d_in[2];
    const float* gn1b = (const float*)d_in[3];
    const float* w2   = (const float*)d_in[4];
    const float* gn2w = (const float*)d_in[5];
    const float* gn2b = (const float*)d_in[6];
    const float* w3   = (const float*)d_in[7];
    const float* gn3w = (const float*)d_in[8];
    const float* gn3b = (const float*)d_in[9];
    const float* w4   = (const float*)d_in[10];
    const float* gn4w = (const float*)d_in[11];
    const float* gn4b = (const float*)d_in[12];
    const float* fc1w = (const float*)d_in[13];
    const float* fc1b = (const float*)d_in[14];
    const float* fc2w = (const float*)d_in[15];
    const float* fc2b = (const float*)d_in[16];
    float* out = (float*)d_out;

    char* ws = (char*)d_ws;
    size_t cur = 0;
    auto alloc = [&](size_t bytes) -> void* {
        cur = (cur + 255) & ~(size_t)255;
        void* p = ws + cur;
        cur += bytes;
        return p;
    };
    int*      counts  = (int*)alloc((size_t)NB * NCHUNK * 4);
    int*      prefix  = (int*)alloc((size_t)NB * NCHUNK * 4);
    int*      totals  = (int*)alloc(64);
    unsigned long long* bits = (unsigned long long*)alloc((size_t)NB * NCHUNK * 16 * 8);
    float*    pts     = (float*)alloc((size_t)NB * 3 * NPTS * 4);
    float*    gbuf    = (float*)alloc((size_t)NB * 512 * 4);
    float*    pstat1  = (float*)alloc((size_t)NB * 8 * 16 * 2 * 4);
    float*    pstatG  = (float*)alloc((size_t)NB * 64 * 256 * 2 * 4);
    float*    pstat4  = (float*)alloc((size_t)NB * 64 * 512 * 4 * 4);
    float*    scale   = (float*)alloc((size_t)NB * 512 * 4);
    float*    shift   = (float*)alloc((size_t)NB * 512 * 4);
    _Float16* w2f     = (_Float16*)alloc((size_t)128 * 64 * 2);
    _Float16* w3f     = (_Float16*)alloc((size_t)256 * 128 * 2);
    _Float16* w4f     = (_Float16*)alloc((size_t)512 * 256 * 2);
    _Float16* y2      = (_Float16*)alloc((size_t)NB * NPTS * 128 * 2);
    _Float16* y3      = (_Float16*)alloc((size_t)NB * NPTS * 256 * 2);

    // 1. mask/count/scan, then points + fused conv1 stats
    count_kernel<<<dim3(NB * NCHUNK), dim3(256), 0, stream>>>(vol, counts, bits);
    scan_kernel<<<dim3(NB), dim3(1024), 0, stream>>>(counts, prefix, totals);
    points_kernel<<<dim3(NB * 16), dim3(256), 0, stream>>>(bits, prefix, totals, w1, pts, pstat1);

    // 2. weight casts
    cast_w_all<<<dim3(84), dim3(256), 0, stream>>>(w2, w3, w4, w2f, w3f, w4f);

    // 3. layer-1 finalize, then fused layer 2 (conv1 recompute + GEMM)
    gn_finalize1<<<dim3(NB * 8), dim3(64), 0, stream>>>(pstat1, gn1w, gn1b, scale, shift);
    fused_l2<<<dim3(64, NB), dim3(256), 0, stream>>>(pts, w1, scale, shift, w2f, y2, pstatG);

    // 4. layer 3
    gn_finalizeG<128><<<dim3(NB * 8), dim3(256), 0, stream>>>(pstatG, gn2w, gn2b, scale, shift);
    fused_layer<128, 256, false><<<dim3(64, NB), dim3(256), 0, stream>>>(y2, scale, shift, w3f, y3, pstatG);

    // 5. layer 4 (pooled epilogue, no y4)
    gn_finalizeG<256><<<dim3(NB * 8), dim3(256), 0, stream>>>(pstatG, gn3w, gn3b, scale, shift);
    fused_layer<256, 512, true><<<dim3(64, NB), dim3(256), 0, stream>>>(y3, scale, shift, w4f, nullptr, pstat4);

    // 6. pool finalize + head
    pool_final<<<dim3(NB * 8), dim3(64), 0, stream>>>(pstat4, gn4w, gn4b, gbuf);
    head_kernel<<<dim3(NB), dim3(128), 0, stream>>>(gbuf, fc1w, fc1b, fc2w, fc2b, out);
}

// Round 8
// 122.551 us; speedup vs baseline: 1.1393x; 1.0283x over previous
//
#include <hip/hip_runtime.h>
#include <hip/hip_bf16.h>

#define NB 16
#define VOX 884736        // 96*96*96
#define NPTS 4096
#define CHUNK 1024
#define NCHUNK 864        // VOX / CHUNK

typedef _Float16 f16x8 __attribute__((ext_vector_type(8)));
typedef _Float16 f16x4 __attribute__((ext_vector_type(4)));
typedef float f32x4 __attribute__((ext_vector_type(4)));

// ---------------- count + bitmask ----------------

__global__ __launch_bounds__(256) void count_kernel(const float* __restrict__ vol,
                                                    int* __restrict__ counts,
                                                    unsigned long long* __restrict__ bits) {
    int blk = blockIdx.x;  // b*NCHUNK + c
    const float4* v4 = (const float4*)(vol + (size_t)blk * CHUNK);
    float4 v = v4[threadIdx.x];
    int nib = (v.x > 0.5f) | ((v.y > 0.5f) << 1) | ((v.z > 0.5f) << 2) | ((v.w > 0.5f) << 3);
    __shared__ unsigned char nibs[256];
    nibs[threadIdx.x] = (unsigned char)nib;
    int cnt = __popc(nib);
    for (int off = 32; off; off >>= 1) cnt += __shfl_down(cnt, off, 64);
    __shared__ int s[4];
    if ((threadIdx.x & 63) == 0) s[threadIdx.x >> 6] = cnt;
    __syncthreads();
    if (threadIdx.x < 16) {
        unsigned long long wd = 0;
        #pragma unroll
        for (int i = 0; i < 16; i++)
            wd |= (unsigned long long)nibs[threadIdx.x * 16 + i] << (4 * i);
        bits[(size_t)blk * 16 + threadIdx.x] = wd;
    }
    if (threadIdx.x == 0) counts[blk] = s[0] + s[1] + s[2] + s[3];
}

__global__ __launch_bounds__(1024) void scan_kernel(const int* __restrict__ counts,
                                                    int* __restrict__ prefix,
                                                    int* __restrict__ totals) {
    __shared__ int s[1024];
    int b = blockIdx.x, t = threadIdx.x;
    int v = (t < NCHUNK) ? counts[b * NCHUNK + t] : 0;
    s[t] = v;
    __syncthreads();
    for (int off = 1; off < 1024; off <<= 1) {
        int x = (t >= off) ? s[t - off] : 0;
        __syncthreads();
        s[t] += x;
        __syncthreads();
    }
    if (t < NCHUNK) prefix[b * NCHUNK + t] = s[t] - v;   // exclusive
    if (t == NCHUNK - 1) totals[b] = s[t];
}

// ---------------- points via bitmask rank-select, fused conv1 stats ----------------

__global__ __launch_bounds__(256) void points_kernel(const unsigned long long* __restrict__ bits,
                                                     const int* __restrict__ prefix,
                                                     const int* __restrict__ totals,
                                                     const float* __restrict__ w1,
                                                     float* __restrict__ pts,
                                                     float* __restrict__ pstat1) {
    int b = blockIdx.x >> 4;
    int pc = blockIdx.x & 15;
    int p = pc * 256 + threadIdx.x;
    __shared__ int spref[NCHUNK];
    __shared__ float sw1[192];
    for (int i = threadIdx.x; i < NCHUNK; i += 256) spref[i] = prefix[b * NCHUNK + i];
    if (threadIdx.x < 192) sw1[threadIdx.x] = w1[threadIdx.x];
    __syncthreads();
    int n = totals[b];
    float px = 0.f, py = 0.f, pz = 0.f;
    if (n > 0) {
        int k;
        if (n >= NPTS) {
            float t = (float)p * ((float)n - 1.0f);
            t = t / 4095.0f;
            k = (int)t;
            if (k > n - 1) k = n - 1;
            if (k < 0) k = 0;
        } else {
            k = p % n;
        }
        int lo = 0, hi = NCHUNK - 1;
        while (lo < hi) {
            int mid = (lo + hi + 1) >> 1;
            if (spref[mid] <= k) lo = mid; else hi = mid - 1;
        }
        int rr = k - spref[lo];
        const unsigned long long* wb = bits + ((size_t)b * NCHUNK + lo) * 16;
        unsigned long long chosen = 0;
        int wordidx = 0;
        bool found = false;
        #pragma unroll
        for (int w = 0; w < 16; w++) {
            unsigned long long m = wb[w];
            int pcnt = __popcll(m);
            bool take = (!found) && (rr < pcnt);
            if (take) { chosen = m; wordidx = w; found = true; }
            if (!found) rr -= pcnt;
        }
        int pos = 0;
        unsigned long long m64 = chosen;
        int c = __popcll(m64 & 0xFFFFFFFFull);
        if (rr >= c) { pos = 32; rr -= c; m64 >>= 32; }
        unsigned mm = (unsigned)m64;
        c = __popc(mm & 0xFFFFu); if (rr >= c) { pos += 16; rr -= c; mm >>= 16; }
        c = __popc(mm & 0xFFu);   if (rr >= c) { pos += 8;  rr -= c; mm >>= 8; }
        c = __popc(mm & 0xFu);    if (rr >= c) { pos += 4;  rr -= c; mm >>= 4; }
        c = __popc(mm & 0x3u);    if (rr >= c) { pos += 2;  rr -= c; mm >>= 2; }
        c = mm & 1u;              if (rr >= c) { pos += 1; }
        int flat = lo * CHUNK + wordidx * 64 + pos;
        int dd = flat / 9216;           // 96*96
        int rem = flat - dd * 9216;
        int hh = rem / 96;
        int ww = rem - hh * 96;
        px = (float)dd / 95.0f * 2.0f - 1.0f;
        py = (float)hh / 95.0f * 2.0f - 1.0f;
        pz = (float)ww / 95.0f * 2.0f - 1.0f;
    }
    pts[((size_t)b * 3 + 0) * NPTS + p] = px;
    pts[((size_t)b * 3 + 1) * NPTS + p] = py;
    pts[((size_t)b * 3 + 2) * NPTS + p] = pz;
    // fused conv1 GN partial stats
    float s[8] = {}, q[8] = {};
    #pragma unroll
    for (int o = 0; o < 64; o++) {
        float a = sw1[o * 3 + 0] * px + sw1[o * 3 + 1] * py + sw1[o * 3 + 2] * pz;
        s[o >> 3] += a;
        q[o >> 3] += a * a;
    }
    __shared__ float red[4][8][2];
    int wv = threadIdx.x >> 6;
    #pragma unroll
    for (int g = 0; g < 8; g++) {
        float S = s[g], Q = q[g];
        for (int off = 32; off; off >>= 1) {
            S += __shfl_down(S, off, 64);
            Q += __shfl_down(Q, off, 64);
        }
        if ((threadIdx.x & 63) == 0) { red[wv][g][0] = S; red[wv][g][1] = Q; }
    }
    __syncthreads();
    if (threadIdx.x < 8) {
        int g = threadIdx.x;
        float S = red[0][g][0] + red[1][g][0] + red[2][g][0] + red[3][g][0];
        float Q = red[0][g][1] + red[1][g][1] + red[2][g][1] + red[3][g][1];
        float* d = pstat1 + (((size_t)(b * 8 + g)) * 16 + pc) * 2;
        d[0] = S; d[1] = Q;
    }
}

__global__ __launch_bounds__(64) void gn_finalize1(const float* __restrict__ pstat,
                                                   const float* __restrict__ gamma,
                                                   const float* __restrict__ beta,
                                                   float* __restrict__ scale,
                                                   float* __restrict__ shift) {
    int b = blockIdx.x >> 3, g = blockIdx.x & 7;
    const float* base = pstat + (size_t)(b * 8 + g) * 32;
    float S = 0.f, Q = 0.f;
    if (threadIdx.x < 16) { S = base[threadIdx.x * 2]; Q = base[threadIdx.x * 2 + 1]; }
    for (int off = 8; off; off >>= 1) {
        S += __shfl_down(S, off, 64);
        Q += __shfl_down(Q, off, 64);
    }
    __shared__ float ms[2];
    if (threadIdx.x == 0) {
        float inv = 1.0f / (8.0f * 4096.0f);
        float mu = S * inv;
        float var = Q * inv - mu * mu;
        if (var < 0.f) var = 0.f;
        ms[0] = mu; ms[1] = rsqrtf(var + 1e-5f);
    }
    __syncthreads();
    if (threadIdx.x < 8) {
        int c = g * 8 + threadIdx.x;
        float ga = gamma[c] * ms[1];
        scale[b * 64 + c] = ga;
        shift[b * 64 + c] = beta[c] - ms[0] * ga;
    }
}

// ---------------- weight cast: all three -> fragment layout ----------------

__device__ inline void cast_chunk(const float* __restrict__ wf, _Float16* __restrict__ wh,
                                  int CIN, int t) {
    int lane = t & 63;
    int NCB = CIN / 32;
    int cb = (t >> 6) % NCB;
    int ob = t / (64 * NCB);
    int o = ob * 16 + (lane & 15);
    int c0 = cb * 32 + (lane >> 4) * 8;
    const float* src = wf + (size_t)o * CIN + c0;
    f16x8 v;
    #pragma unroll
    for (int e = 0; e < 8; e++) v[e] = (_Float16)src[e];
    *(f16x8*)(wh + (size_t)t * 8) = v;
}

__global__ __launch_bounds__(256) void cast_w_all(const float* __restrict__ w2,
                                                  const float* __restrict__ w3,
                                                  const float* __restrict__ w4,
                                                  _Float16* __restrict__ w2f,
                                                  _Float16* __restrict__ w3f,
                                                  _Float16* __restrict__ w4f) {
    int t = blockIdx.x * 256 + threadIdx.x;
    if (t < 1024) cast_chunk(w2, w2f, 64, t);
    else if (t < 1024 + 4096) cast_chunk(w3, w3f, 128, t - 1024);
    else if (t < 1024 + 4096 + 16384) cast_chunk(w4, w4f, 256, t - 5120);
}

// ---------------- GEMM core v2: wave owns 32 points x COUT/2 channels ----------------
// sl: staged 64 x CIN fp16 tile, slot = ch ^ (p & (CIN/8-1)) swizzle.
// pstat at 32-point granularity: [b][128][COUT][NST], direct from registers.

template <int CIN, int COUT, bool POOL>
__device__ __forceinline__ void gemm_core(const _Float16* __restrict__ sl,
                                          const _Float16* __restrict__ wfrag,
                                          _Float16* __restrict__ yout,
                                          float* __restrict__ pstat,
                                          int b, int pblk, int tid) {
    constexpr int NCB = CIN / 32;
    constexpr int SLOT = CIN / 8 - 1;
    constexpr int OFW = COUT / 32;          // of-frags per wave (wave covers COUT/2)
    constexpr int COF = OFW > 4 ? 4 : OFW;
    constexpr int NCHK = OFW / COF;
    int wv = tid >> 6, lane = tid & 63, lr = lane & 15, lk = lane >> 4;
    int ph = wv & 1, oh = wv >> 1;
    int Pg = b * 64 + pblk;
    int pb32 = (Pg << 1) | ph;
    #pragma unroll
    for (int ck = 0; ck < NCHK; ck++) {
        f32x4 acc[2][COF] = {};
        for (int cb = 0; cb < NCB; cb++) {
            int ch = cb * 4 + lk;
            f16x8 af[2];
            #pragma unroll
            for (int pf = 0; pf < 2; pf++) {
                int p = ph * 32 + pf * 16 + lr;
                af[pf] = *(const f16x8*)(sl + p * CIN + ((ch ^ (p & SLOT)) << 3));
            }
            f16x8 bf[COF];
            #pragma unroll
            for (int i = 0; i < COF; i++) {
                int ofr = oh * OFW + ck * COF + i;
                bf[i] = *(const f16x8*)(wfrag + ((size_t)(ofr * NCB + cb) * 64 + lane) * 8);
            }
            #pragma unroll
            for (int pf = 0; pf < 2; pf++)
                #pragma unroll
                for (int i = 0; i < COF; i++)
                    acc[pf][i] = __builtin_amdgcn_mfma_f32_16x16x32_f16(af[pf], bf[i], acc[pf][i], 0, 0, 0);
        }
        #pragma unroll
        for (int i = 0; i < COF; i++) {
            int ofr = oh * OFW + ck * COF + i;
            if (!POOL) {
                _Float16* ytO = yout + ((size_t)Pg * (COUT / 64) + (ofr >> 2)) * 4096;
                #pragma unroll
                for (int pf = 0; pf < 2; pf++) {
                    f16x4 vv;
                    #pragma unroll
                    for (int j = 0; j < 4; j++) vv[j] = (_Float16)acc[pf][i][j];
                    *(f16x4*)(ytO + (((ofr & 3) * 4 + ph * 2 + pf) * 64 + lane) * 4) = vv;
                }
            }
            float S = 0.f, Q = 0.f, MX = -1e30f, MN = 1e30f;
            #pragma unroll
            for (int pf = 0; pf < 2; pf++)
                #pragma unroll
                for (int j = 0; j < 4; j++) {
                    float v = acc[pf][i][j];
                    S += v; Q += v * v;
                    if (POOL) { MX = fmaxf(MX, v); MN = fminf(MN, v); }
                }
            S += __shfl_xor(S, 16, 64); Q += __shfl_xor(Q, 16, 64);
            S += __shfl_xor(S, 32, 64); Q += __shfl_xor(Q, 32, 64);
            if (POOL) {
                MX = fmaxf(MX, __shfl_xor(MX, 16, 64)); MN = fminf(MN, __shfl_xor(MN, 16, 64));
                MX = fmaxf(MX, __shfl_xor(MX, 32, 64)); MN = fminf(MN, __shfl_xor(MN, 32, 64));
            }
            if (lk == 0) {
                int o = ofr * 16 + lr;
                if (POOL) {
                    *(float4*)(pstat + ((size_t)pb32 * COUT + o) * 4) = make_float4(S, Q, MX, MN);
                } else {
                    float* d = pstat + ((size_t)pb32 * COUT + o) * 2;
                    d[0] = S; d[1] = Q;
                }
            }
        }
    }
}

// ---------------- fused layer 2: conv1+GN+ReLU stage -> GEMM ----------------

__global__ __launch_bounds__(256, 4) void fused_l2(const float* __restrict__ pts,
                                                   const float* __restrict__ w1,
                                                   const float* __restrict__ scale,
                                                   const float* __restrict__ shift,
                                                   const _Float16* __restrict__ wfrag,
                                                   _Float16* __restrict__ yout,
                                                   float* __restrict__ pstat) {
    __shared__ _Float16 sl[64 * 64];
    __shared__ float sw1[192], ssc[64], ssh[64];
    int b = blockIdx.y, pblk = blockIdx.x, tid = threadIdx.x;
    if (tid < 192) sw1[tid] = w1[tid];
    if (tid < 64) { ssc[tid] = scale[b * 64 + tid]; ssh[tid] = shift[b * 64 + tid]; }
    __syncthreads();
    {   // stage: recompute conv1 + norm + relu -> swizzled LDS (slot = ch ^ (p&7))
        int p = tid >> 2, qo = (tid & 3) * 16;
        int pg = pblk * 64 + p;
        float x0 = pts[((size_t)b * 3 + 0) * NPTS + pg];
        float x1 = pts[((size_t)b * 3 + 1) * NPTS + pg];
        float x2 = pts[((size_t)b * 3 + 2) * NPTS + pg];
        #pragma unroll
        for (int e = 0; e < 16; e++) {
            int o = qo + e;
            float a = sw1[o * 3 + 0] * x0 + sw1[o * 3 + 1] * x1 + sw1[o * 3 + 2] * x2;
            float r = fmaxf(a * ssc[o] + ssh[o], 0.f);
            sl[p * 64 + (((o >> 3) ^ (p & 7)) << 3) + (o & 7)] = (_Float16)r;
        }
    }
    __syncthreads();
    gemm_core<64, 128, false>(sl, wfrag, yout, pstat, b, pblk, tid);
}

// ---------------- fused layers 3,4: D-native stage -> GEMM ----------------

template <int CIN, int COUT, bool POOL>
__global__ __launch_bounds__(256, 4) void fused_layer(const _Float16* __restrict__ yprev,
                                                      const float* __restrict__ scale,
                                                      const float* __restrict__ shift,
                                                      const _Float16* __restrict__ wfrag,
                                                      _Float16* __restrict__ yout,
                                                      float* __restrict__ pstat) {
    constexpr int SLOT = CIN / 8 - 1;
    __shared__ _Float16 sl[64 * CIN];
    __shared__ float ssc[CIN], ssh[CIN];
    int b = blockIdx.y, pblk = blockIdx.x, tid = threadIdx.x;
    int Pg = b * 64 + pblk;
    for (int i = tid; i < CIN; i += 256) { ssc[i] = scale[b * CIN + i]; ssh[i] = shift[b * CIN + i]; }
    __syncthreads();
    const _Float16* yt = yprev + (size_t)Pg * 64 * CIN;
    constexpr int NCH4 = 64 * CIN / 4;
    for (int q = tid; q < NCH4; q += 256) {
        int lane = q & 63;
        int pf = (q >> 6) & 3;
        int ofi = (q >> 8) & 3;
        int Ob = q >> 10;
        int o = Ob * 64 + ofi * 16 + (lane & 15);
        int pbase = pf * 16 + (lane >> 4) * 4;
        f16x4 v = *(const f16x4*)(yt + (size_t)q * 4);
        float sc = ssc[o], sh = ssh[o];
        int ch = o >> 3;
        #pragma unroll
        for (int e = 0; e < 4; e++) {
            int p = pbase + e;
            float r = fmaxf((float)v[e] * sc + sh, 0.f);
            sl[p * CIN + ((ch ^ (p & SLOT)) << 3) + (o & 7)] = (_Float16)r;
        }
    }
    __syncthreads();
    gemm_core<CIN, COUT, POOL>(sl, wfrag, yout, pstat, b, pblk, tid);
}

// ---------------- GN finalize (layers 2,3): pstat[b][128][C][2] -> scale/shift ----------------

template <int C>
__global__ __launch_bounds__(256) void gn_finalizeG(const float* __restrict__ pstat,
                                                    const float* __restrict__ gamma,
                                                    const float* __restrict__ beta,
                                                    float* __restrict__ scale,
                                                    float* __restrict__ shift) {
    constexpr int GS = C / 8;
    int b = blockIdx.x >> 3, g = blockIdx.x & 7;
    const float* base = pstat + (size_t)b * 128 * C * 2;
    float S = 0.f, Q = 0.f;
    for (int i = threadIdx.x; i < 128 * GS; i += 256) {
        int pb = i / GS;
        int c = g * GS + (i % GS);
        const float* d = base + ((size_t)pb * C + c) * 2;
        S += d[0]; Q += d[1];
    }
    for (int off = 32; off; off >>= 1) {
        S += __shfl_down(S, off, 64);
        Q += __shfl_down(Q, off, 64);
    }
    __shared__ float ss[8];
    if ((threadIdx.x & 63) == 0) {
        ss[(threadIdx.x >> 6) * 2] = S;
        ss[(threadIdx.x >> 6) * 2 + 1] = Q;
    }
    __syncthreads();
    __shared__ float ms[2];
    if (threadIdx.x == 0) {
        float St = ss[0] + ss[2] + ss[4] + ss[6];
        float Qt = ss[1] + ss[3] + ss[5] + ss[7];
        float inv = 1.0f / ((float)GS * 4096.0f);
        float mu = St * inv;
        float var = Qt * inv - mu * mu;
        if (var < 0.f) var = 0.f;
        ms[0] = mu; ms[1] = rsqrtf(var + 1e-5f);
    }
    __syncthreads();
    for (int i = threadIdx.x; i < GS; i += 256) {
        int c = g * GS + i;
        float ga = gamma[c] * ms[1];
        scale[(size_t)b * C + c] = ga;
        shift[(size_t)b * C + c] = beta[c] - ms[0] * ga;
    }
}

// ---------------- pool finalize: one wave per (b, group); pstat4[b][128][512][4] ----------------

__global__ __launch_bounds__(64) void pool_final(const float* __restrict__ pstat4,
                                                 const float* __restrict__ gamma,
                                                 const float* __restrict__ beta,
                                                 float* __restrict__ g) {
    int b = blockIdx.x >> 3, gr = blockIdx.x & 7;
    int o = gr * 64 + threadIdx.x;
    float S = 0.f, Q = 0.f, MX = -1e30f, MN = 1e30f;
    for (int pb = 0; pb < 128; pb++) {
        float4 v = *(const float4*)(pstat4 + (((size_t)(b * 128 + pb)) * 512 + o) * 4);
        S += v.x; Q += v.y; MX = fmaxf(MX, v.z); MN = fminf(MN, v.w);
    }
    float St = S, Qt = Q;
    for (int off = 32; off; off >>= 1) {
        St += __shfl_xor(St, off, 64);
        Qt += __shfl_xor(Qt, off, 64);
    }
    float inv = 1.0f / (64.0f * 4096.0f);
    float mu = St * inv;
    float var = Qt * inv - mu * mu;
    if (var < 0.f) var = 0.f;
    float rstd = rsqrtf(var + 1e-5f);
    float sc = gamma[o] * rstd;
    float sh = beta[o] - mu * sc;
    float m = (sc >= 0.f ? MX : MN) * sc + sh;
    g[b * 512 + o] = fmaxf(m, 0.f);
}

// ---------------- FC head ----------------

__global__ __launch_bounds__(128) void head_kernel(const float* __restrict__ g,
                                                   const float* __restrict__ fc1w,
                                                   const float* __restrict__ fc1b,
                                                   const float* __restrict__ fc2w,
                                                   const float* __restrict__ fc2b,
                                                   float* __restrict__ out) {
    int b = blockIdx.x;
    int o = threadIdx.x;   // 128
    __shared__ float sg[512];
    for (int i = threadIdx.x; i < 512; i += 128) sg[i] = g[b * 512 + i];
    __syncthreads();
    float acc = fc1b[o];
    for (int c = 0; c < 512; c++) acc += sg[c] * fc1w[o * 512 + c];
    float h = fmaxf(acc, 0.f) * fc2w[o];
    for (int off = 32; off; off >>= 1) h += __shfl_down(h, off, 64);
    __shared__ float s2[2];
    if ((threadIdx.x & 63) == 0) s2[threadIdx.x >> 6] = h;
    __syncthreads();
    if (threadIdx.x == 0) out[b] = s2[0] + s2[1] + fc2b[0];
}

// ---------------- launch ----------------

extern "C" void kernel_launch(void* const* d_in, const int* in_sizes, int n_in,
                              void* d_out, int out_size, void* d_ws, size_t ws_size,
                              hipStream_t stream) {
    const float* vol  = (const float*)d_in[0];
    const float* w1   = (const float*)d_in[1];
    const float* gn1w = (const float*)d_in[2];
    const float* gn1b = (const float*)d_in[3];
    const float* w2   = (const float*)d_in[4];
    const float* gn2w = (const float*)d_in[5];
    const float* gn2b = (const float*)d_in[6];
    const float* w3   = (const float*)d_in[7];
    const float* gn3w = (const float*)d_in[8];
    const float* gn3b = (const float*)d_in[9];
    const float* w4   = (const float*)d_in[10];
    const float* gn4w = (const float*)d_in[11];
    const float* gn4b = (const float*)d_in[12];
    const float* fc1w = (const float*)d_in[13];
    const float* fc1b = (const float*)d_in[14];
    const float* fc2w = (const float*)d_in[15];
    const float* fc2b = (const float*)d_in[16];
    float* out = (float*)d_out;

    char* ws = (char*)d_ws;
    size_t cur = 0;
    auto alloc = [&](size_t bytes) -> void* {
        cur = (cur + 255) & ~(size_t)255;
        void* p = ws + cur;
        cur += bytes;
        return p;
    };
    int*      counts  = (int*)alloc((size_t)NB * NCHUNK * 4);
    int*      prefix  = (int*)alloc((size_t)NB * NCHUNK * 4);
    int*      totals  = (int*)alloc(64);
    unsigned long long* bits = (unsigned long long*)alloc((size_t)NB * NCHUNK * 16 * 8);
    float*    pts     = (float*)alloc((size_t)NB * 3 * NPTS * 4);
    float*    gbuf    = (float*)alloc((size_t)NB * 512 * 4);
    float*    pstat1  = (float*)alloc((size_t)NB * 8 * 16 * 2 * 4);
    float*    pstatG  = (float*)alloc((size_t)NB * 128 * 256 * 2 * 4);
    float*    pstat4  = (float*)alloc((size_t)NB * 128 * 512 * 4 * 4);
    float*    scale   = (float*)alloc((size_t)NB * 512 * 4);
    float*    shift   = (float*)alloc((size_t)NB * 512 * 4);
    _Float16* w2f     = (_Float16*)alloc((size_t)128 * 64 * 2);
    _Float16* w3f     = (_Float16*)alloc((size_t)256 * 128 * 2);
    _Float16* w4f     = (_Float16*)alloc((size_t)512 * 256 * 2);
    _Float16* y2      = (_Float16*)alloc((size_t)NB * NPTS * 128 * 2);
    _Float16* y3      = (_Float16*)alloc((size_t)NB * NPTS * 256 * 2);

    // 1. mask/count/scan, then points + fused conv1 stats
    count_kernel<<<dim3(NB * NCHUNK), dim3(256), 0, stream>>>(vol, counts, bits);
    scan_kernel<<<dim3(NB), dim3(1024), 0, stream>>>(counts, prefix, totals);
    points_kernel<<<dim3(NB * 16), dim3(256), 0, stream>>>(bits, prefix, totals, w1, pts, pstat1);

    // 2. weight casts
    cast_w_all<<<dim3(84), dim3(256), 0, stream>>>(w2, w3, w4, w2f, w3f, w4f);

    // 3. layer-1 finalize, then fused layer 2 (conv1 recompute + GEMM)
    gn_finalize1<<<dim3(NB * 8), dim3(64), 0, stream>>>(pstat1, gn1w, gn1b, scale, shift);
    fused_l2<<<dim3(64, NB), dim3(256), 0, stream>>>(pts, w1, scale, shift, w2f, y2, pstatG);

    // 4. layer 3
    gn_finalizeG<128><<<dim3(NB * 8), dim3(256), 0, stream>>>(pstatG, gn2w, gn2b, scale, shift);
    fused_layer<128, 256, false><<<dim3(64, NB), dim3(256), 0, stream>>>(y2, scale, shift, w3f, y3, pstatG);

    // 5. layer 4 (pooled epilogue, no y4)
    gn_finalizeG<256><<<dim3(NB * 8), dim3(256), 0, stream>>>(pstatG, gn3w, gn3b, scale, shift);
    fused_layer<256, 512, true><<<dim3(64, NB), dim3(256), 0, stream>>>(y3, scale, shift, w4f, nullptr, pstat4);

    // 6. pool finalize + head
    pool_final<<<dim3(NB * 8), dim3(64), 0, stream>>>(pstat4, gn4w, gn4b, gbuf);
    head_kernel<<<dim3(NB), dim3(128), 0, stream>>>(gbuf, fc1w, fc1b, fc2w, fc2b, out);
}